// Round 1
// baseline (65.134 us; speedup 1.0000x reference)
//
#include <hip/hip_runtime.h>

// Chamfer distance, fp32 brute force.
// rows 0..32767   : predict points (b = r>>13, n = r&8191), cols = target[b]
// rows 32768..65535: target points, cols = predict[b]
// Per row: min over 8192 cols of (||t||^2 - 2 p.t), then + ||p||^2.
// out = (sum over all 65536 rows) / 32768.

#define NPTS   8192
#define NB     4
#define HALF   32768            // NB * NPTS
#define NROWS  65536            // 2 * HALF
#define NCHUNK 16               // col chunks
#define CW     512              // 8192 / NCHUNK
#define P      8                // rows per thread
#define RPB    2048             // rows per block = 256 * P
#define NRB    32               // NROWS / RPB

__global__ __launch_bounds__(256) void pack_kernel(
    const float* __restrict__ predict, const float* __restrict__ target,
    float4* __restrict__ packed)
{
    int r = blockIdx.x * 256 + threadIdx.x;
    const float* src = (r < HALF) ? (predict + (size_t)r * 3)
                                  : (target + (size_t)(r - HALF) * 3);
    float x = src[0], y = src[1], z = src[2];
    float nrm = fmaf(x, x, fmaf(y, y, z * z));
    packed[r] = make_float4(x, y, z, nrm);
}

__global__ __launch_bounds__(256) void minpart_kernel(
    const float4* __restrict__ packed, float* __restrict__ partial)
{
    __shared__ float4 sm[CW];                 // 8 KB
    const int rb   = blockIdx.x >> 4;         // / NCHUNK
    const int cb   = blockIdx.x & (NCHUNK - 1);
    const int row0 = rb * RPB;
    const int sideA = (row0 < HALF) ? 1 : 0;
    const int local = sideA ? row0 : row0 - HALF;
    const int b = local >> 13;                // / NPTS
    const int colBase = (sideA ? HALF : 0) + (b << 13) + cb * CW;

    for (int i = threadIdx.x; i < CW; i += 256)
        sm[i] = packed[colBase + i];
    __syncthreads();

    float px[P], py[P], pz[P], mn[P];
    #pragma unroll
    for (int j = 0; j < P; ++j) {
        float4 p = packed[row0 + threadIdx.x + j * 256];
        px[j] = p.x; py[j] = p.y; pz[j] = p.z;
        mn[j] = 3.4e38f;
    }

    #pragma unroll 4
    for (int i = 0; i < CW; ++i) {
        float4 t = sm[i];                     // uniform addr -> LDS broadcast
        #pragma unroll
        for (int j = 0; j < P; ++j) {
            float dot = fmaf(px[j], t.x, fmaf(py[j], t.y, pz[j] * t.z));
            float s   = fmaf(-2.0f, dot, t.w);
            mn[j] = fminf(mn[j], s);
        }
    }

    #pragma unroll
    for (int j = 0; j < P; ++j)
        partial[(size_t)cb * NROWS + row0 + threadIdx.x + j * 256] = mn[j];
}

__global__ __launch_bounds__(256) void reduce_kernel(
    const float4* __restrict__ packed, const float* __restrict__ partial,
    float* __restrict__ blockSums)
{
    int r = blockIdx.x * 256 + threadIdx.x;
    float m = 3.4e38f;
    #pragma unroll
    for (int c = 0; c < NCHUNK; ++c)
        m = fminf(m, partial[(size_t)c * NROWS + r]);
    float val = m + packed[r].w;              // + ||p||^2

    __shared__ float red[256];
    red[threadIdx.x] = val;
    __syncthreads();
    for (int s = 128; s > 0; s >>= 1) {
        if (threadIdx.x < s) red[threadIdx.x] += red[threadIdx.x + s];
        __syncthreads();
    }
    if (threadIdx.x == 0) blockSums[blockIdx.x] = red[0];
}

__global__ __launch_bounds__(256) void final_kernel(
    const float* __restrict__ blockSums, float* __restrict__ out)
{
    __shared__ float red[256];
    red[threadIdx.x] = blockSums[threadIdx.x];
    __syncthreads();
    for (int s = 128; s > 0; s >>= 1) {
        if (threadIdx.x < s) red[threadIdx.x] += red[threadIdx.x + s];
        __syncthreads();
    }
    if (threadIdx.x == 0) out[0] = red[0] * (1.0f / (float)HALF);
}

extern "C" void kernel_launch(void* const* d_in, const int* in_sizes, int n_in,
                              void* d_out, int out_size, void* d_ws, size_t ws_size,
                              hipStream_t stream)
{
    const float* predict = (const float*)d_in[0];
    const float* target  = (const float*)d_in[1];
    float* out = (float*)d_out;

    char* ws = (char*)d_ws;
    float4* packed   = (float4*)ws;                                   // 1 MB
    float*  partial  = (float*)(ws + (size_t)NROWS * sizeof(float4)); // 4 MB
    float*  blockSums = (float*)(ws + (size_t)NROWS * sizeof(float4)
                                    + (size_t)NROWS * NCHUNK * sizeof(float)); // 1 KB

    pack_kernel   <<<NROWS / 256,  256, 0, stream>>>(predict, target, packed);
    minpart_kernel<<<NRB * NCHUNK, 256, 0, stream>>>(packed, partial);
    reduce_kernel <<<NROWS / 256,  256, 0, stream>>>(packed, partial, blockSums);
    final_kernel  <<<1,            256, 0, stream>>>(blockSums, out);
}

// Round 2
// 55.625 us; speedup vs baseline: 1.1709x; 1.1709x over previous
//
#include <hip/hip_runtime.h>

// Chamfer distance, fp32 brute force, VALU-optimized.
// rows 0..32767    : predict points (b = r>>13), cols = target[b]
// rows 32768..65535: target points,              cols = predict[b]
// Per row: min over 8192 cols of (||t||^2 - 2 p.t), then + ||p||^2.
// out = (sum over all 65536 rows) / 32768.
//
// Inner loop: q = -2p folded per-row; s = fma(qx,tx,fma(qy,ty,fma(qz,tz,tw)))
// = 3 fma/pair; columns processed in pairs so the min fold is
// fminf(fminf(mn,s0),s1) -> v_min3_f32 = 0.5 inst/pair. 3.5 VALU/pair.

#define NPTS   8192
#define HALF   32768            // 4 * NPTS
#define NROWS  65536
#define P      16               // rows per thread
#define RPB    4096             // rows per block = 256 * P
#define NRB    16               // NROWS / RPB

__global__ __launch_bounds__(256) void pack_kernel(
    const float* __restrict__ predict, const float* __restrict__ target,
    float4* __restrict__ packed)
{
    int r = blockIdx.x * 256 + threadIdx.x;
    const float* src = (r < HALF) ? (predict + (size_t)r * 3)
                                  : (target + (size_t)(r - HALF) * 3);
    float x = src[0], y = src[1], z = src[2];
    float nrm = fmaf(x, x, fmaf(y, y, z * z));
    packed[r] = make_float4(x, y, z, nrm);
}

template<int NCH>
__global__ __launch_bounds__(256) void minpart_kernel(
    const float4* __restrict__ packed, float* __restrict__ partial)
{
    constexpr int CW = NPTS / NCH;            // cols per chunk
    __shared__ float4 sm[CW];
    const int rb   = blockIdx.x / NCH;
    const int cb   = blockIdx.x % NCH;
    const int row0 = rb * RPB;
    const bool sideA = (row0 < HALF);
    const int local = sideA ? row0 : row0 - HALF;
    const int b = local >> 13;                // / NPTS
    const int colBase = (sideA ? HALF : 0) + (b << 13) + cb * CW;

    for (int i = threadIdx.x; i < CW; i += 256)
        sm[i] = packed[colBase + i];
    __syncthreads();

    float qx[P], qy[P], qz[P], mn[P];
    #pragma unroll
    for (int j = 0; j < P; ++j) {
        float4 p = packed[row0 + threadIdx.x + j * 256];
        qx[j] = -2.0f * p.x; qy[j] = -2.0f * p.y; qz[j] = -2.0f * p.z;
        mn[j] = 3.4e38f;
    }

    #pragma unroll 2
    for (int i = 0; i < CW; i += 2) {
        float4 t0 = sm[i];                    // uniform addr -> LDS broadcast
        float4 t1 = sm[i + 1];
        #pragma unroll
        for (int j = 0; j < P; ++j) {
            float s0 = fmaf(qx[j], t0.x, fmaf(qy[j], t0.y, fmaf(qz[j], t0.z, t0.w)));
            float s1 = fmaf(qx[j], t1.x, fmaf(qy[j], t1.y, fmaf(qz[j], t1.z, t1.w)));
            mn[j] = fminf(fminf(mn[j], s0), s1);   // -> v_min3_f32
        }
    }

    #pragma unroll
    for (int j = 0; j < P; ++j)
        partial[(size_t)cb * NROWS + row0 + threadIdx.x + j * 256] = mn[j];
}

template<int NCH>
__global__ __launch_bounds__(256) void reduce_kernel(
    const float4* __restrict__ packed, const float* __restrict__ partial,
    float* __restrict__ blockSums)
{
    int r = blockIdx.x * 256 + threadIdx.x;
    float m = 3.4e38f;
    #pragma unroll
    for (int c = 0; c < NCH; ++c)
        m = fminf(m, partial[(size_t)c * NROWS + r]);
    float val = m + packed[r].w;              // + ||p||^2

    __shared__ float red[256];
    red[threadIdx.x] = val;
    __syncthreads();
    for (int s = 128; s > 0; s >>= 1) {
        if (threadIdx.x < s) red[threadIdx.x] += red[threadIdx.x + s];
        __syncthreads();
    }
    if (threadIdx.x == 0) blockSums[blockIdx.x] = red[0];
}

__global__ __launch_bounds__(256) void final_kernel(
    const float* __restrict__ blockSums, float* __restrict__ out)
{
    __shared__ float red[256];
    red[threadIdx.x] = blockSums[threadIdx.x];
    __syncthreads();
    for (int s = 128; s > 0; s >>= 1) {
        if (threadIdx.x < s) red[threadIdx.x] += red[threadIdx.x + s];
        __syncthreads();
    }
    if (threadIdx.x == 0) out[0] = red[0] * (1.0f / (float)HALF);
}

extern "C" void kernel_launch(void* const* d_in, const int* in_sizes, int n_in,
                              void* d_out, int out_size, void* d_ws, size_t ws_size,
                              hipStream_t stream)
{
    const float* predict = (const float*)d_in[0];
    const float* target  = (const float*)d_in[1];
    float* out = (float*)d_out;

    char* ws = (char*)d_ws;
    float4* packed = (float4*)ws;                                  // 1 MB
    float*  partial = (float*)(ws + (size_t)NROWS * sizeof(float4));

    pack_kernel<<<NROWS / 256, 256, 0, stream>>>(predict, target, packed);

    const size_t need32 = (size_t)NROWS * sizeof(float4)
                        + (size_t)NROWS * 32 * sizeof(float) + 4096;
    if (ws_size >= need32) {
        constexpr int NCH = 32;               // 512 blocks = 2/CU
        float* blockSums = (float*)(ws + (size_t)NROWS * sizeof(float4)
                                       + (size_t)NROWS * NCH * sizeof(float));
        minpart_kernel<NCH><<<NRB * NCH, 256, 0, stream>>>(packed, partial);
        reduce_kernel<NCH><<<NROWS / 256, 256, 0, stream>>>(packed, partial, blockSums);
        final_kernel<<<1, 256, 0, stream>>>(blockSums, out);
    } else {
        constexpr int NCH = 16;               // fallback: 4 MB partial
        float* blockSums = (float*)(ws + (size_t)NROWS * sizeof(float4)
                                       + (size_t)NROWS * NCH * sizeof(float));
        minpart_kernel<NCH><<<NRB * NCH, 256, 0, stream>>>(packed, partial);
        reduce_kernel<NCH><<<NROWS / 256, 256, 0, stream>>>(packed, partial, blockSums);
        final_kernel<<<1, 256, 0, stream>>>(blockSums, out);
    }
}